// Round 2
// baseline (161.611 us; speedup 1.0000x reference)
//
#include <hip/hip_runtime.h>
#include <hip/hip_bf16.h>
#include <cstdint>
#include <cstddef>

// StreamingAttentionBlock: B=2, T=2048, DIM=1024, H=16, hd=64, window=3 keys
// I/O dtypes: ALL fp32 (reference uses jnp.float32). Internal compute: bf16 MFMA
// (threshold 7.8e-2 is bf16-grade), fp32 accumulation.
#define T_SEQ 2048
#define NBATCH 2
#define DIMSZ 1024
#define NHEAD 16
#define HDIM 64

typedef float f32x4 __attribute__((ext_vector_type(4)));
typedef short bf16x8 __attribute__((ext_vector_type(8)));

// async global->LDS, 16B per lane. LDS dest = wave-uniform base + lane*16.
__device__ __forceinline__ void gld_lds16(const __hip_bfloat16* g, __hip_bfloat16* l) {
    __builtin_amdgcn_global_load_lds(
        (const __attribute__((address_space(1))) unsigned int*)g,
        (__attribute__((address_space(3))) unsigned int*)l,
        16, 0, 0);
}

// -------- fp32 -> bf16 convert (vectorized, n % 1024 == 0) --------
__global__ __launch_bounds__(256) void cvt_f32_bf16(
    const float* __restrict__ in, __hip_bfloat16* __restrict__ out)
{
    int i = (blockIdx.x * 256 + threadIdx.x) * 4;
    float4 v = *(const float4*)(in + i);
    union { __hip_bfloat16 h[4]; ushort4 u; } pk;
    pk.h[0] = __hip_bfloat16(v.x); pk.h[1] = __hip_bfloat16(v.y);
    pk.h[2] = __hip_bfloat16(v.z); pk.h[3] = __hip_bfloat16(v.w);
    *(ushort4*)(out + i) = pk.u;
}

// -------- fused convert + transpose: fp32 (R x C) -> bf16 (C x R) --------
__global__ __launch_bounds__(256) void ct_f32_bf16(
    const float* __restrict__ in, __hip_bfloat16* __restrict__ out, int R, int C)
{
    __shared__ float tile[32][33];
    const int c0 = blockIdx.x * 32, r0 = blockIdx.y * 32;
    const int tx = threadIdx.x & 31, ty = threadIdx.x >> 5;   // ty 0..7
#pragma unroll
    for (int p = 0; p < 32; p += 8)
        tile[ty + p][tx] = in[(size_t)(r0 + ty + p) * C + c0 + tx];
    __syncthreads();
#pragma unroll
    for (int p = 0; p < 32; p += 8)
        out[(size_t)(c0 + ty + p) * R + r0 + tx] = __hip_bfloat16(tile[tx][ty + p]);
}

// -------- GEMM: C(MxN) = A(MxK) @ Bt(NxK)^T [+ fp32 bias], bf16 in, fp32 accum --------
// 128x128 tile, BK=32, 256 threads = 4 waves (2x2), each wave 64x64 via 4x4 MFMA 16x16x32.
template<bool HAS_BIAS, typename OutT>
__global__ __launch_bounds__(256) void gemm_bt(
    const __hip_bfloat16* __restrict__ A,
    const __hip_bfloat16* __restrict__ Bt,
    const float* __restrict__ bias,
    OutT* __restrict__ C,
    int M, int N, int K)
{
    __shared__ __align__(16) __hip_bfloat16 As[128 * 32];
    __shared__ __align__(16) __hip_bfloat16 Bs[128 * 32];

    const int tid  = threadIdx.x;
    const int wv   = tid >> 6;
    const int lane = tid & 63;
    const int bn   = blockIdx.x, bm = blockIdx.y;
    const int wm   = wv >> 1, wn = wv & 1;

    f32x4 acc[4][4] = {};

    const int srow = lane >> 2;          // 0..15
    const int scol = (lane & 3) * 8;     // 0,8,16,24  (16B per lane)

    const __hip_bfloat16* Ag = A  + (size_t)(bm * 128) * K;
    const __hip_bfloat16* Bg = Bt + (size_t)(bn * 128) * K;

    const int fm = lane & 15;
    const int fq = (lane >> 4) * 8;

    for (int kk = 0; kk < K; kk += 32) {
#pragma unroll
        for (int it = 0; it < 2; ++it) {
            int row = (it * 4 + wv) * 16 + srow;          // 0..127
            gld_lds16(Ag + (size_t)row * K + kk + scol, As + row * 32 + scol);
            gld_lds16(Bg + (size_t)row * K + kk + scol, Bs + row * 32 + scol);
        }
        __syncthreads();

        bf16x8 af[4], bfr[4];
#pragma unroll
        for (int i = 0; i < 4; ++i)
            af[i] = *(const bf16x8*)(As + (wm * 64 + i * 16 + fm) * 32 + fq);
#pragma unroll
        for (int j = 0; j < 4; ++j)
            bfr[j] = *(const bf16x8*)(Bs + (wn * 64 + j * 16 + fm) * 32 + fq);

#pragma unroll
        for (int i = 0; i < 4; ++i)
#pragma unroll
            for (int j = 0; j < 4; ++j)
                acc[i][j] = __builtin_amdgcn_mfma_f32_16x16x32_bf16(af[i], bfr[j], acc[i][j], 0, 0, 0);
        __syncthreads();
    }

    // epilogue: C/D layout col=lane&15, row=(lane>>4)*4+reg  [m89-verified]
    const int fcol  = lane & 15;
    const int frow4 = (lane >> 4) * 4;
    const int cm0 = bm * 128 + wm * 64;
    const int cn0 = bn * 128 + wn * 64;
#pragma unroll
    for (int j = 0; j < 4; ++j) {
        int col = cn0 + j * 16 + fcol;
        float bv = HAS_BIAS ? bias[col] : 0.0f;
#pragma unroll
        for (int i = 0; i < 4; ++i) {
#pragma unroll
            for (int r = 0; r < 4; ++r) {
                int row = cm0 + i * 16 + frow4 + r;
                C[(size_t)row * N + col] = OutT(acc[i][j][r] + bv);
            }
        }
    }
}

// -------- banded attention: one wave per (b,t,h); keys j = t..t+2 (clamped) --------
__global__ __launch_bounds__(256) void attn_banded(
    const __hip_bfloat16* __restrict__ qkv,   // (B*T, 3*DIM): [q | k | v]
    __hip_bfloat16* __restrict__ o)           // (B*T, DIM)
{
    const int lane = threadIdx.x & 63;                     // = d within head
    const int wid  = blockIdx.x * 4 + (threadIdx.x >> 6);  // (b*T+t)*H + h
    const int h = wid & (NHEAD - 1);
    const int r = wid >> 4;            // b*T + t
    const int t = r & (T_SEQ - 1);     // position within batch
    const size_t rb = (size_t)r * (3 * DIMSZ);
    const int hc = h * HDIM + lane;

    float q = (float)qkv[rb + hc];
    float s[3], vv[3];
#pragma unroll
    for (int j = 0; j < 3; ++j) {
        bool ok = (t + j) < T_SEQ;     // masks both seq end and batch boundary
        size_t rbj = ok ? rb + (size_t)j * (3 * DIMSZ) : rb;
        float kj = (float)qkv[rbj + DIMSZ + hc];
        vv[j]    = (float)qkv[rbj + 2 * DIMSZ + hc];
        float d = q * kj;
#pragma unroll
        for (int off = 32; off > 0; off >>= 1)
            d += __shfl_xor(d, off, 64);
        s[j] = ok ? d * 0.125f : -1e30f;   // scale = 64^-0.5; big-negative avoids inf math
    }
    float m = fmaxf(s[0], fmaxf(s[1], s[2]));
    float p0 = __expf(s[0] - m), p1 = __expf(s[1] - m), p2 = __expf(s[2] - m);
    float inv = 1.0f / (p0 + p1 + p2);
    float out = (p0 * vv[0] + p1 * vv[1] + p2 * vv[2]) * inv;
    o[(size_t)r * DIMSZ + hc] = __hip_bfloat16(out);
}

extern "C" void kernel_launch(void* const* d_in, const int* in_sizes, int n_in,
                              void* d_out, int out_size, void* d_ws, size_t ws_size,
                              hipStream_t stream) {
    const float* x      = (const float*)d_in[0];  // (B,T,DIM) fp32
    const float* w_qkv  = (const float*)d_in[1];  // (DIM, 3*DIM) fp32
    const float* w_proj = (const float*)d_in[2];  // (DIM, DIM) fp32
    const float* b_proj = (const float*)d_in[3];  // (DIM,) fp32
    float* out = (float*)d_out;                   // (B,T,DIM) fp32

    const int M = NBATCH * T_SEQ;   // 4096

    // workspace (bf16 intermediates), 40 MB total:
    //   [0,8M)  xb   (x in bf16)  -> reused as attn output after GEMM1
    //   [8M,14M) wqkvT  (3072x1024)
    //   [14M,16M) wprojT (1024x1024)
    //   [16M,40M) qkv   (4096x3072)
    char* ws = (char*)d_ws;
    __hip_bfloat16* xb     = (__hip_bfloat16*)(ws);
    __hip_bfloat16* attn   = (__hip_bfloat16*)(ws);            // reuse of xb region
    __hip_bfloat16* wqkvT  = (__hip_bfloat16*)(ws + (8u  << 20));
    __hip_bfloat16* wprojT = (__hip_bfloat16*)(ws + (14u << 20));
    __hip_bfloat16* qkv    = (__hip_bfloat16*)(ws + (16u << 20));

    // 1) convert x to bf16
    cvt_f32_bf16<<<(M * DIMSZ) / 1024, 256, 0, stream>>>(x, xb);

    // 2) convert+transpose weights into Bt (NxK, k-contiguous) bf16
    ct_f32_bf16<<<dim3(3 * DIMSZ / 32, DIMSZ / 32), 256, 0, stream>>>(w_qkv, wqkvT, DIMSZ, 3 * DIMSZ);
    ct_f32_bf16<<<dim3(DIMSZ / 32, DIMSZ / 32), 256, 0, stream>>>(w_proj, wprojT, DIMSZ, DIMSZ);

    // 3) qkv = x @ w_qkv   (4096 x 3072, K=1024), bf16 out
    gemm_bt<false, __hip_bfloat16><<<dim3(3 * DIMSZ / 128, M / 128), 256, 0, stream>>>(
        xb, wqkvT, nullptr, qkv, M, 3 * DIMSZ, DIMSZ);

    // 4) banded attention (3-key window), writes bf16 attn into xb region (xb dead)
    attn_banded<<<M * NHEAD / 4, 256, 0, stream>>>(qkv, attn);

    // 5) out = attn @ w_proj + b_proj  (4096 x 1024, K=1024), fp32 out
    gemm_bt<true, float><<<dim3(DIMSZ / 128, M / 128), 256, 0, stream>>>(
        attn, wprojT, b_proj, out, M, DIMSZ, DIMSZ);
}

// Round 3
// 154.426 us; speedup vs baseline: 1.0465x; 1.0465x over previous
//
#include <hip/hip_runtime.h>
#include <hip/hip_bf16.h>
#include <cstdint>
#include <cstddef>

// StreamingAttentionBlock: B=2, T=2048, DIM=1024, H=16, hd=64, window=3 keys
// I/O: fp32. Internal: bf16 MFMA, fp32 accumulation. (R2 passed: absmax 0.0156)
#define T_SEQ 2048
#define NBATCH 2
#define DIMSZ 1024
#define NHEAD 16
#define HDIM 64

typedef float f32x4 __attribute__((ext_vector_type(4)));
typedef short bf16x8 __attribute__((ext_vector_type(8)));

// async global->LDS, 16B per lane. LDS dest = wave-uniform base + lane*16.
__device__ __forceinline__ void gld_lds16(const __hip_bfloat16* g, __hip_bfloat16* l) {
    __builtin_amdgcn_global_load_lds(
        (const __attribute__((address_space(1))) unsigned int*)g,
        (__attribute__((address_space(3))) unsigned int*)l,
        16, 0, 0);
}

// -------- fused prep: convert x -> bf16; convert+transpose both weights --------
// grid: [0,4096)   convert x (4096x1024 fp32 -> bf16, 4 elem/thread)
//       [4096,7168) ct w_qkv (1024x3072 -> 3072x1024 bf16), 32x32 tiles, 96 per row
//       [7168,8192) ct w_proj (1024x1024 -> 1024x1024 bf16), 32 per row
__global__ __launch_bounds__(256) void prep(
    const float* __restrict__ x,      __hip_bfloat16* __restrict__ xb,
    const float* __restrict__ wqkv,   __hip_bfloat16* __restrict__ wqkvT,
    const float* __restrict__ wproj,  __hip_bfloat16* __restrict__ wprojT)
{
    __shared__ float tile[32][33];
    const int b = blockIdx.x;
    if (b < 4096) {
        int i = (b * 256 + threadIdx.x) * 4;
        float4 v = *(const float4*)(x + i);
        union { __hip_bfloat16 h[4]; ushort4 u; } pk;
        pk.h[0] = __hip_bfloat16(v.x); pk.h[1] = __hip_bfloat16(v.y);
        pk.h[2] = __hip_bfloat16(v.z); pk.h[3] = __hip_bfloat16(v.w);
        *(ushort4*)(xb + i) = pk.u;
        return;
    }
    const float* in; __hip_bfloat16* out; int R, C, c0, r0;
    if (b < 7168) {
        int bb = b - 4096; in = wqkv; out = wqkvT; R = 1024; C = 3072;
        c0 = (bb % 96) * 32; r0 = (bb / 96) * 32;
    } else {
        int bb = b - 7168; in = wproj; out = wprojT; R = 1024; C = 1024;
        c0 = (bb & 31) * 32; r0 = (bb >> 5) * 32;
    }
    const int tx = threadIdx.x & 31, ty = threadIdx.x >> 5;   // ty 0..7
#pragma unroll
    for (int p = 0; p < 32; p += 8)
        tile[ty + p][tx] = in[(size_t)(r0 + ty + p) * C + c0 + tx];
    __syncthreads();
#pragma unroll
    for (int p = 0; p < 32; p += 8)
        out[(size_t)(c0 + ty + p) * R + r0 + tx] = __hip_bfloat16(tile[tx][ty + p]);
}

// -------- GEMM1: C(MxN) = A(MxK) @ Bt(NxK)^T, bf16 out --------
// 128x128 tile, BK=32, 4 waves (2x2), wave = 64x64 via 4x4 MFMA 16x16x32.
__global__ __launch_bounds__(256) void gemm_bt_128(
    const __hip_bfloat16* __restrict__ A,
    const __hip_bfloat16* __restrict__ Bt,
    __hip_bfloat16* __restrict__ C,
    int M, int N, int K)
{
    __shared__ __align__(16) __hip_bfloat16 As[128 * 32];
    __shared__ __align__(16) __hip_bfloat16 Bs[128 * 32];

    const int tid  = threadIdx.x;
    const int wv   = tid >> 6;
    const int lane = tid & 63;
    const int bn   = blockIdx.x, bm = blockIdx.y;
    const int wm   = wv >> 1, wn = wv & 1;

    f32x4 acc[4][4] = {};

    const int srow = lane >> 2;          // 0..15
    const int scol = (lane & 3) * 8;     // 16B per lane

    const __hip_bfloat16* Ag = A  + (size_t)(bm * 128) * K;
    const __hip_bfloat16* Bg = Bt + (size_t)(bn * 128) * K;

    const int fm = lane & 15;
    const int fq = (lane >> 4) * 8;

    for (int kk = 0; kk < K; kk += 32) {
#pragma unroll
        for (int it = 0; it < 2; ++it) {
            int row = (it * 4 + wv) * 16 + srow;          // 0..127
            gld_lds16(Ag + (size_t)row * K + kk + scol, As + row * 32 + scol);
            gld_lds16(Bg + (size_t)row * K + kk + scol, Bs + row * 32 + scol);
        }
        __syncthreads();

        bf16x8 af[4], bfr[4];
#pragma unroll
        for (int i = 0; i < 4; ++i)
            af[i] = *(const bf16x8*)(As + (wm * 64 + i * 16 + fm) * 32 + fq);
#pragma unroll
        for (int j = 0; j < 4; ++j)
            bfr[j] = *(const bf16x8*)(Bs + (wn * 64 + j * 16 + fm) * 32 + fq);

#pragma unroll
        for (int i = 0; i < 4; ++i)
#pragma unroll
            for (int j = 0; j < 4; ++j)
                acc[i][j] = __builtin_amdgcn_mfma_f32_16x16x32_bf16(af[i], bfr[j], acc[i][j], 0, 0, 0);
        __syncthreads();
    }

    // C/D layout: col=lane&15, row=(lane>>4)*4+reg  [m89-verified]
    const int fcol  = lane & 15;
    const int frow4 = (lane >> 4) * 4;
    const int cm0 = bm * 128 + wm * 64;
    const int cn0 = bn * 128 + wn * 64;
#pragma unroll
    for (int j = 0; j < 4; ++j) {
        int col = cn0 + j * 16 + fcol;
#pragma unroll
        for (int i = 0; i < 4; ++i)
#pragma unroll
            for (int r = 0; r < 4; ++r) {
                int row = cm0 + i * 16 + frow4 + r;
                C[(size_t)row * N + col] = __hip_bfloat16(acc[i][j][r]);
            }
    }
}

// -------- GEMM2: 64x128 tile (2 blocks/CU for the 4096x1024 shape), fp32 out + bias --------
// 4 waves (2x2), wave = 32x64 via 2x4 MFMA 16x16x32.
__global__ __launch_bounds__(256) void gemm_bt_64(
    const __hip_bfloat16* __restrict__ A,
    const __hip_bfloat16* __restrict__ Bt,
    const float* __restrict__ bias,
    float* __restrict__ C,
    int M, int N, int K)
{
    __shared__ __align__(16) __hip_bfloat16 As[64 * 32];
    __shared__ __align__(16) __hip_bfloat16 Bs[128 * 32];

    const int tid  = threadIdx.x;
    const int wv   = tid >> 6;
    const int lane = tid & 63;
    const int bn   = blockIdx.x, bm = blockIdx.y;
    const int wm   = wv >> 1, wn = wv & 1;

    f32x4 acc[2][4] = {};

    const int srow = lane >> 2;
    const int scol = (lane & 3) * 8;

    const __hip_bfloat16* Ag = A  + (size_t)(bm * 64) * K;
    const __hip_bfloat16* Bg = Bt + (size_t)(bn * 128) * K;

    const int fm = lane & 15;
    const int fq = (lane >> 4) * 8;

    for (int kk = 0; kk < K; kk += 32) {
        {
            int row = wv * 16 + srow;                     // 0..63
            gld_lds16(Ag + (size_t)row * K + kk + scol, As + row * 32 + scol);
        }
#pragma unroll
        for (int it = 0; it < 2; ++it) {
            int row = (it * 4 + wv) * 16 + srow;          // 0..127
            gld_lds16(Bg + (size_t)row * K + kk + scol, Bs + row * 32 + scol);
        }
        __syncthreads();

        bf16x8 af[2], bfr[4];
#pragma unroll
        for (int i = 0; i < 2; ++i)
            af[i] = *(const bf16x8*)(As + (wm * 32 + i * 16 + fm) * 32 + fq);
#pragma unroll
        for (int j = 0; j < 4; ++j)
            bfr[j] = *(const bf16x8*)(Bs + (wn * 64 + j * 16 + fm) * 32 + fq);

#pragma unroll
        for (int i = 0; i < 2; ++i)
#pragma unroll
            for (int j = 0; j < 4; ++j)
                acc[i][j] = __builtin_amdgcn_mfma_f32_16x16x32_bf16(af[i], bfr[j], acc[i][j], 0, 0, 0);
        __syncthreads();
    }

    const int fcol  = lane & 15;
    const int frow4 = (lane >> 4) * 4;
    const int cm0 = bm * 64 + wm * 32;
    const int cn0 = bn * 128 + wn * 64;
#pragma unroll
    for (int j = 0; j < 4; ++j) {
        int col = cn0 + j * 16 + fcol;
        float bv = bias[col];
#pragma unroll
        for (int i = 0; i < 2; ++i)
#pragma unroll
            for (int r = 0; r < 4; ++r) {
                int row = cm0 + i * 16 + frow4 + r;
                C[(size_t)row * N + col] = acc[i][j][r] + bv;
            }
    }
}

// -------- banded attention: one wave per (b,t,h); keys j = t..t+2 (clamped) --------
__global__ __launch_bounds__(256) void attn_banded(
    const __hip_bfloat16* __restrict__ qkv,   // (B*T, 3*DIM): [q | k | v]
    __hip_bfloat16* __restrict__ o)           // (B*T, DIM)
{
    const int lane = threadIdx.x & 63;                     // = d within head
    const int wid  = blockIdx.x * 4 + (threadIdx.x >> 6);  // (b*T+t)*H + h
    const int h = wid & (NHEAD - 1);
    const int r = wid >> 4;            // b*T + t
    const int t = r & (T_SEQ - 1);     // position within batch
    const size_t rb = (size_t)r * (3 * DIMSZ);
    const int hc = h * HDIM + lane;

    float q = (float)qkv[rb + hc];
    float s[3], vv[3];
#pragma unroll
    for (int j = 0; j < 3; ++j) {
        bool ok = (t + j) < T_SEQ;     // masks both seq end and batch boundary
        size_t rbj = ok ? rb + (size_t)j * (3 * DIMSZ) : rb;
        float kj = (float)qkv[rbj + DIMSZ + hc];
        vv[j]    = (float)qkv[rbj + 2 * DIMSZ + hc];
        float d = q * kj;
#pragma unroll
        for (int off = 32; off > 0; off >>= 1)
            d += __shfl_xor(d, off, 64);
        s[j] = ok ? d * 0.125f : -1e30f;   // scale = 64^-0.5
    }
    float m = fmaxf(s[0], fmaxf(s[1], s[2]));
    float p0 = __expf(s[0] - m), p1 = __expf(s[1] - m), p2 = __expf(s[2] - m);
    float inv = 1.0f / (p0 + p1 + p2);
    float out = (p0 * vv[0] + p1 * vv[1] + p2 * vv[2]) * inv;
    o[(size_t)r * DIMSZ + hc] = __hip_bfloat16(out);
}

extern "C" void kernel_launch(void* const* d_in, const int* in_sizes, int n_in,
                              void* d_out, int out_size, void* d_ws, size_t ws_size,
                              hipStream_t stream) {
    const float* x      = (const float*)d_in[0];  // (B,T,DIM) fp32
    const float* w_qkv  = (const float*)d_in[1];  // (DIM, 3*DIM) fp32
    const float* w_proj = (const float*)d_in[2];  // (DIM, DIM) fp32
    const float* b_proj = (const float*)d_in[3];  // (DIM,) fp32
    float* out = (float*)d_out;                   // (B,T,DIM) fp32

    const int M = NBATCH * T_SEQ;   // 4096

    // workspace (bf16 intermediates):
    //   [0,8M)    xb (x bf16)  -> reused as attn output after GEMM1 consumes it
    //   [8M,14M)  wqkvT  (3072x1024)
    //   [14M,16M) wprojT (1024x1024)
    //   [16M,40M) qkv    (4096x3072)
    char* ws = (char*)d_ws;
    __hip_bfloat16* xb     = (__hip_bfloat16*)(ws);
    __hip_bfloat16* attn   = (__hip_bfloat16*)(ws);            // reuse of xb region
    __hip_bfloat16* wqkvT  = (__hip_bfloat16*)(ws + (8u  << 20));
    __hip_bfloat16* wprojT = (__hip_bfloat16*)(ws + (14u << 20));
    __hip_bfloat16* qkv    = (__hip_bfloat16*)(ws + (16u << 20));

    // 1) fused prep: x->bf16, both weight convert+transposes
    prep<<<8192, 256, 0, stream>>>(x, xb, w_qkv, wqkvT, w_proj, wprojT);

    // 2) qkv = x @ w_qkv   (4096 x 3072, K=1024): 24x32=768 blocks = 3/CU
    gemm_bt_128<<<dim3(3 * DIMSZ / 128, M / 128), 256, 0, stream>>>(
        xb, wqkvT, qkv, M, 3 * DIMSZ, DIMSZ);

    // 3) banded attention (3-key window) -> bf16 attn (reuses xb region)
    attn_banded<<<M * NHEAD / 4, 256, 0, stream>>>(qkv, attn);

    // 4) out = attn @ w_proj + b_proj  (4096 x 1024): 8x64=512 blocks = 2/CU
    gemm_bt_64<<<dim3(DIMSZ / 128, M / 64), 256, 0, stream>>>(
        attn, wprojT, b_proj, out, M, DIMSZ, DIMSZ);
}

// Round 4
// 145.215 us; speedup vs baseline: 1.1129x; 1.0634x over previous
//
#include <hip/hip_runtime.h>
#include <hip/hip_bf16.h>
#include <cstdint>
#include <cstddef>

// StreamingAttentionBlock: B=2, T=2048, DIM=1024, H=16, hd=64, window=3 keys
// I/O: fp32. Internal: bf16 MFMA, fp32 accumulation. (R2/R3 passed: absmax 0.0156)
#define T_SEQ 2048
#define NBATCH 2
#define DIMSZ 1024
#define NHEAD 16
#define HDIM 64

typedef float f32x4 __attribute__((ext_vector_type(4)));
typedef short bf16x8 __attribute__((ext_vector_type(8)));

// async global->LDS, 16B per lane. LDS dest = wave-uniform base + lane*16.
__device__ __forceinline__ void gld_lds16(const __hip_bfloat16* g, __hip_bfloat16* l) {
    __builtin_amdgcn_global_load_lds(
        (const __attribute__((address_space(1))) unsigned int*)g,
        (__attribute__((address_space(3))) unsigned int*)l,
        16, 0, 0);
}

__device__ __forceinline__ float bf2f(unsigned short u) {
    union { unsigned int i; float f; } c; c.i = (unsigned int)u << 16; return c.f;
}

// -------- fused prep: convert x -> bf16; convert+transpose both weights --------
__global__ __launch_bounds__(256) void prep(
    const float* __restrict__ x,      __hip_bfloat16* __restrict__ xb,
    const float* __restrict__ wqkv,   __hip_bfloat16* __restrict__ wqkvT,
    const float* __restrict__ wproj,  __hip_bfloat16* __restrict__ wprojT)
{
    __shared__ float tile[32][33];
    const int b = blockIdx.x;
    if (b < 4096) {
        int i = (b * 256 + threadIdx.x) * 4;
        float4 v = *(const float4*)(x + i);
        union { __hip_bfloat16 h[4]; ushort4 u; } pk;
        pk.h[0] = __hip_bfloat16(v.x); pk.h[1] = __hip_bfloat16(v.y);
        pk.h[2] = __hip_bfloat16(v.z); pk.h[3] = __hip_bfloat16(v.w);
        *(ushort4*)(xb + i) = pk.u;
        return;
    }
    const float* in; __hip_bfloat16* out; int R, C, c0, r0;
    if (b < 7168) {
        int bb = b - 4096; in = wqkv; out = wqkvT; R = 1024; C = 3072;
        c0 = (bb % 96) * 32; r0 = (bb / 96) * 32;
    } else {
        int bb = b - 7168; in = wproj; out = wprojT; R = 1024; C = 1024;
        c0 = (bb & 31) * 32; r0 = (bb >> 5) * 32;
    }
    const int tx = threadIdx.x & 31, ty = threadIdx.x >> 5;
#pragma unroll
    for (int p = 0; p < 32; p += 8)
        tile[ty + p][tx] = in[(size_t)(r0 + ty + p) * C + c0 + tx];
    __syncthreads();
#pragma unroll
    for (int p = 0; p < 32; p += 8)
        out[(size_t)(c0 + ty + p) * R + r0 + tx] = __hip_bfloat16(tile[tx][ty + p]);
}

// -------- GEMM1: 128x128 tile, BK=64 as two m97-style 32-wide sub-tiles --------
// LDS layout [kh][row][32] keeps gld_lds16 lane-contiguity AND the proven
// conflict-free ds_read_b128 fragment pattern; halves barrier count vs BK=32.
__global__ __launch_bounds__(256) void gemm_bt_128(
    const __hip_bfloat16* __restrict__ A,
    const __hip_bfloat16* __restrict__ Bt,
    __hip_bfloat16* __restrict__ C,
    int M, int N, int K)
{
    __shared__ __align__(16) __hip_bfloat16 As[2 * 128 * 32];
    __shared__ __align__(16) __hip_bfloat16 Bs[2 * 128 * 32];

    const int tid  = threadIdx.x;
    const int wv   = tid >> 6;
    const int lane = tid & 63;
    const int bn   = blockIdx.x, bm = blockIdx.y;
    const int wm   = wv >> 1, wn = wv & 1;

    f32x4 acc[4][4] = {};

    const int srow = lane >> 2;          // 0..15
    const int scol = (lane & 3) * 8;     // 16B per lane

    const __hip_bfloat16* Ag = A  + (size_t)(bm * 128) * K;
    const __hip_bfloat16* Bg = Bt + (size_t)(bn * 128) * K;

    const int fm = lane & 15;
    const int fq = (lane >> 4) * 8;

    for (int kk = 0; kk < K; kk += 64) {
#pragma unroll
        for (int kh = 0; kh < 2; ++kh)
#pragma unroll
            for (int it = 0; it < 2; ++it) {
                int row = (it * 4 + wv) * 16 + srow;          // 0..127
                gld_lds16(Ag + (size_t)row * K + kk + kh * 32 + scol,
                          As + kh * 4096 + row * 32 + scol);
                gld_lds16(Bg + (size_t)row * K + kk + kh * 32 + scol,
                          Bs + kh * 4096 + row * 32 + scol);
            }
        __syncthreads();

#pragma unroll
        for (int kh = 0; kh < 2; ++kh) {
            bf16x8 af[4], bfr[4];
#pragma unroll
            for (int i = 0; i < 4; ++i)
                af[i] = *(const bf16x8*)(As + kh * 4096 + (wm * 64 + i * 16 + fm) * 32 + fq);
#pragma unroll
            for (int j = 0; j < 4; ++j)
                bfr[j] = *(const bf16x8*)(Bs + kh * 4096 + (wn * 64 + j * 16 + fm) * 32 + fq);
#pragma unroll
            for (int i = 0; i < 4; ++i)
#pragma unroll
                for (int j = 0; j < 4; ++j)
                    acc[i][j] = __builtin_amdgcn_mfma_f32_16x16x32_bf16(af[i], bfr[j], acc[i][j], 0, 0, 0);
        }
        __syncthreads();
    }

    // C/D layout: col=lane&15, row=(lane>>4)*4+reg  [m89-verified]
    const int fcol  = lane & 15;
    const int frow4 = (lane >> 4) * 4;
    const int cm0 = bm * 128 + wm * 64;
    const int cn0 = bn * 128 + wn * 64;
#pragma unroll
    for (int j = 0; j < 4; ++j) {
        int col = cn0 + j * 16 + fcol;
#pragma unroll
        for (int i = 0; i < 4; ++i)
#pragma unroll
            for (int r = 0; r < 4; ++r) {
                int row = cm0 + i * 16 + frow4 + r;
                C[(size_t)row * N + col] = __hip_bfloat16(acc[i][j][r]);
            }
    }
}

// -------- GEMM2: 64x128 tile, BK=64 (512 blocks = 2/CU), fp32 out + bias --------
__global__ __launch_bounds__(256) void gemm_bt_64(
    const __hip_bfloat16* __restrict__ A,
    const __hip_bfloat16* __restrict__ Bt,
    const float* __restrict__ bias,
    float* __restrict__ C,
    int M, int N, int K)
{
    __shared__ __align__(16) __hip_bfloat16 As[2 * 64 * 32];
    __shared__ __align__(16) __hip_bfloat16 Bs[2 * 128 * 32];

    const int tid  = threadIdx.x;
    const int wv   = tid >> 6;
    const int lane = tid & 63;
    const int bn   = blockIdx.x, bm = blockIdx.y;
    const int wm   = wv >> 1, wn = wv & 1;

    f32x4 acc[2][4] = {};

    const int srow = lane >> 2;
    const int scol = (lane & 3) * 8;

    const __hip_bfloat16* Ag = A  + (size_t)(bm * 64) * K;
    const __hip_bfloat16* Bg = Bt + (size_t)(bn * 128) * K;

    const int fm = lane & 15;
    const int fq = (lane >> 4) * 8;

    for (int kk = 0; kk < K; kk += 64) {
#pragma unroll
        for (int kh = 0; kh < 2; ++kh) {
            {
                int row = wv * 16 + srow;                     // 0..63
                gld_lds16(Ag + (size_t)row * K + kk + kh * 32 + scol,
                          As + kh * 2048 + row * 32 + scol);
            }
#pragma unroll
            for (int it = 0; it < 2; ++it) {
                int row = (it * 4 + wv) * 16 + srow;          // 0..127
                gld_lds16(Bg + (size_t)row * K + kk + kh * 32 + scol,
                          Bs + kh * 4096 + row * 32 + scol);
            }
        }
        __syncthreads();

#pragma unroll
        for (int kh = 0; kh < 2; ++kh) {
            bf16x8 af[2], bfr[4];
#pragma unroll
            for (int i = 0; i < 2; ++i)
                af[i] = *(const bf16x8*)(As + kh * 2048 + (wm * 32 + i * 16 + fm) * 32 + fq);
#pragma unroll
            for (int j = 0; j < 4; ++j)
                bfr[j] = *(const bf16x8*)(Bs + kh * 4096 + (wn * 64 + j * 16 + fm) * 32 + fq);
#pragma unroll
            for (int i = 0; i < 2; ++i)
#pragma unroll
                for (int j = 0; j < 4; ++j)
                    acc[i][j] = __builtin_amdgcn_mfma_f32_16x16x32_bf16(af[i], bfr[j], acc[i][j], 0, 0, 0);
        }
        __syncthreads();
    }

    const int fcol  = lane & 15;
    const int frow4 = (lane >> 4) * 4;
    const int cm0 = bm * 64 + wm * 32;
    const int cn0 = bn * 128 + wn * 64;
#pragma unroll
    for (int j = 0; j < 4; ++j) {
        int col = cn0 + j * 16 + fcol;
        float bv = bias[col];
#pragma unroll
        for (int i = 0; i < 2; ++i)
#pragma unroll
            for (int r = 0; r < 4; ++r) {
                int row = cm0 + i * 16 + frow4 + r;
                C[(size_t)row * N + col] = acc[i][j][r] + bv;
            }
    }
}

// -------- banded attention, vectorized: one block per token, thread = 4-dim chunk --------
// 16 threads per head (4 dims each); score reduction over 16-lane groups (4 shfl_xor).
__global__ __launch_bounds__(256) void attn_banded(
    const __hip_bfloat16* __restrict__ qkv,   // (B*T, 3*DIM): [q | k | v]
    __hip_bfloat16* __restrict__ o)           // (B*T, DIM)
{
    const int t4 = threadIdx.x;          // dim-chunk index: dims [4*t4, 4*t4+4)
    const int r  = blockIdx.x;           // b*T + t
    const int t  = r & (T_SEQ - 1);
    const size_t rb = (size_t)r * (3 * DIMSZ);
    const int d0 = t4 * 4;

    ushort4 qu = *(const ushort4*)(qkv + rb + d0);
    float q0 = bf2f(qu.x), q1 = bf2f(qu.y), q2 = bf2f(qu.z), q3 = bf2f(qu.w);

    float s[3];
    float vvx[3], vvy[3], vvz[3], vvw[3];
#pragma unroll
    for (int j = 0; j < 3; ++j) {
        bool ok = (t + j) < T_SEQ;       // masks seq end (and batch boundary)
        size_t rbj = ok ? rb + (size_t)j * (3 * DIMSZ) : rb;
        ushort4 ku = *(const ushort4*)(qkv + rbj + DIMSZ + d0);
        ushort4 vu = *(const ushort4*)(qkv + rbj + 2 * DIMSZ + d0);
        vvx[j] = bf2f(vu.x); vvy[j] = bf2f(vu.y); vvz[j] = bf2f(vu.z); vvw[j] = bf2f(vu.w);
        float d = q0 * bf2f(ku.x) + q1 * bf2f(ku.y) + q2 * bf2f(ku.z) + q3 * bf2f(ku.w);
#pragma unroll
        for (int off = 8; off > 0; off >>= 1)
            d += __shfl_xor(d, off, 64);  // reduce within 16-lane head group
        s[j] = ok ? d * 0.125f : -1e30f;  // scale = 64^-0.5
    }
    float m  = fmaxf(s[0], fmaxf(s[1], s[2]));
    float p0 = __expf(s[0] - m), p1 = __expf(s[1] - m), p2 = __expf(s[2] - m);
    float inv = 1.0f / (p0 + p1 + p2);
    union { __hip_bfloat16 h[4]; ushort4 u; } pk;
    pk.h[0] = __hip_bfloat16((p0 * vvx[0] + p1 * vvx[1] + p2 * vvx[2]) * inv);
    pk.h[1] = __hip_bfloat16((p0 * vvy[0] + p1 * vvy[1] + p2 * vvy[2]) * inv);
    pk.h[2] = __hip_bfloat16((p0 * vvz[0] + p1 * vvz[1] + p2 * vvz[2]) * inv);
    pk.h[3] = __hip_bfloat16((p0 * vvw[0] + p1 * vvw[1] + p2 * vvw[2]) * inv);
    *(ushort4*)(o + (size_t)r * DIMSZ + d0) = pk.u;
}

extern "C" void kernel_launch(void* const* d_in, const int* in_sizes, int n_in,
                              void* d_out, int out_size, void* d_ws, size_t ws_size,
                              hipStream_t stream) {
    const float* x      = (const float*)d_in[0];  // (B,T,DIM) fp32
    const float* w_qkv  = (const float*)d_in[1];  // (DIM, 3*DIM) fp32
    const float* w_proj = (const float*)d_in[2];  // (DIM, DIM) fp32
    const float* b_proj = (const float*)d_in[3];  // (DIM,) fp32
    float* out = (float*)d_out;                   // (B,T,DIM) fp32

    const int M = NBATCH * T_SEQ;   // 4096

    // workspace (bf16 intermediates):
    //   [0,8M)    xb (x bf16)  -> reused as attn output after GEMM1 consumes it
    //   [8M,14M)  wqkvT  (3072x1024)
    //   [14M,16M) wprojT (1024x1024)
    //   [16M,40M) qkv    (4096x3072)
    char* ws = (char*)d_ws;
    __hip_bfloat16* xb     = (__hip_bfloat16*)(ws);
    __hip_bfloat16* attn   = (__hip_bfloat16*)(ws);            // reuse of xb region
    __hip_bfloat16* wqkvT  = (__hip_bfloat16*)(ws + (8u  << 20));
    __hip_bfloat16* wprojT = (__hip_bfloat16*)(ws + (14u << 20));
    __hip_bfloat16* qkv    = (__hip_bfloat16*)(ws + (16u << 20));

    // 1) fused prep: x->bf16, both weight convert+transposes
    prep<<<8192, 256, 0, stream>>>(x, xb, w_qkv, wqkvT, w_proj, wprojT);

    // 2) qkv = x @ w_qkv   (4096 x 3072, K=1024): 24x32=768 blocks = 3/CU
    gemm_bt_128<<<dim3(3 * DIMSZ / 128, M / 128), 256, 0, stream>>>(
        xb, wqkvT, qkv, M, 3 * DIMSZ, DIMSZ);

    // 3) banded attention (3-key window) -> bf16 attn (reuses xb region)
    attn_banded<<<M, 256, 0, stream>>>(qkv, attn);

    // 4) out = attn @ w_proj + b_proj  (4096 x 1024): 8x64=512 blocks = 2/CU
    gemm_bt_64<<<dim3(DIMSZ / 128, M / 64), 256, 0, stream>>>(
        attn, wprojT, b_proj, out, M, DIMSZ, DIMSZ);
}